// Round 4
// baseline (900.189 us; speedup 1.0000x reference)
//
#include <hip/hip_runtime.h>
#include <hip/hip_fp16.h>
#include <cstdint>
#include <cstddef>

// Problem constants
constexpr int HD   = 512;          // hidden
constexpr int SQ   = 512;          // seq len
constexpr int NB   = 32;           // batch
constexpr int LAY  = 3;            // layers
constexpr int WID  = 4;            // conv width
constexpr int KIN  = (WID + 1) * HD;   // 2560
constexpr int PROW = SQ + 2 * WID;     // 520 padded rows
constexpr int MR   = NB * SQ;          // 16384 GEMM rows
constexpr int PSTR = NB * PROW * HD;   // pad buffer stride (elems)

typedef _Float16 f16x8 __attribute__((ext_vector_type(8)));
typedef float    f32x4 __attribute__((ext_vector_type(4)));

#define VMCNT(n) asm volatile("s_waitcnt vmcnt(" #n ")" ::: "memory")
#define LGKM0()  asm volatile("s_waitcnt lgkmcnt(0)" ::: "memory")
#define SBAR()   asm volatile("s_barrier" ::: "memory")

__device__ __forceinline__ void gld16(void* lds, const void* g) {
  __builtin_amdgcn_global_load_lds(
      (__attribute__((address_space(1))) void*)(g),
      (__attribute__((address_space(3))) void*)(lds),
      16, 0, 0);
}

// Read one f16x8 MFMA fragment from a 256x32 region (swizzled).
// Region layout: LDS chunk (l&3) of row r=l>>2 holds global k-chunk (l&3)^((r>>1)&3).
__device__ __forceinline__ f16x8 rdfrag(const _Float16* reg, int row, int q) {
  return *(const f16x8*)&reg[row * 32 + ((q ^ ((row >> 1) & 3)) << 3)];
}

// ---------------------------------------------------------------------------
// Paired weight transpose+convert: fp32 [nsl][R][C] x2 -> fp16 [nsl][C][R] x2
// ilv=1: pair-interleave output rows (row 2j = col j, row 2j+1 = col half+j).
// ---------------------------------------------------------------------------
__global__ void transpose_w2(const float* __restrict__ inF, const float* __restrict__ inB,
                             _Float16* __restrict__ outF, _Float16* __restrict__ outB,
                             int R, int C, int nsl, int ilv) {
  __shared__ float tile[32][33];
  const int z = blockIdx.z;
  const float* in = (z < nsl) ? inF : inB;
  _Float16* out   = (z < nsl) ? outF : outB;
  const int sl    = (z < nsl) ? z : z - nsl;
  const size_t base = (size_t)sl * R * C;
  const int r0 = blockIdx.y * 32, c0 = blockIdx.x * 32;
  const int tx = threadIdx.x, ty = threadIdx.y;  // (32, 8)
  const int half = C >> 1;
#pragma unroll
  for (int j = 0; j < 32; j += 8)
    tile[ty + j][tx] = in[base + (size_t)(r0 + ty + j) * C + (c0 + tx)];
  __syncthreads();
#pragma unroll
  for (int j = 0; j < 32; j += 8) {
    const int c = c0 + ty + j;
    const int cc = ilv ? (((c & (half - 1)) << 1) | (c >= half ? 1 : 0)) : c;
    out[base + (size_t)cc * R + (r0 + tx)] = (_Float16)tile[tx][ty + j];
  }
}

// ---------------------------------------------------------------------------
__global__ void init_interior(const float4* __restrict__ in,
                              _Float16* __restrict__ padF, _Float16* __restrict__ padB) {
  const size_t idx = (size_t)blockIdx.x * 256 + threadIdx.x;
  float4 v = in[idx];
  const size_t e = idx * 4;
  const int h = (int)(e & (HD - 1));
  const size_t bt = e >> 9;
  const int t = (int)(bt & (SQ - 1));
  const int b = (int)(bt >> 9);
  const size_t o = ((size_t)(b * PROW + WID + t)) * HD + h;
  union { _Float16 hh[4]; uint2 u; } pk;
  pk.hh[0] = (_Float16)v.x; pk.hh[1] = (_Float16)v.y;
  pk.hh[2] = (_Float16)v.z; pk.hh[3] = (_Float16)v.w;
  *(uint2*)&padF[o] = pk.u;
  *(uint2*)&padB[o] = pk.u;
}

// ---------------------------------------------------------------------------
__global__ void fill_all_pads(const float* __restrict__ fpads, const float* __restrict__ bpads,
                              _Float16* __restrict__ padF, _Float16* __restrict__ padB) {
  const int idx = blockIdx.x * 256 + threadIdx.x;
  const int h  = idx & (HD - 1);
  const int w  = (idx >> 9) & 3;
  const int b  = (idx >> 11) & 31;
  const int fb = (idx >> 16) & 1;
  const int l  = idx >> 17;
  const float v = fb ? bpads[l * WID * HD + w * HD + h] : fpads[l * WID * HD + w * HD + h];
  const int row = fb ? (SQ + WID + w) : w;
  const size_t o = (size_t)l * PSTR + ((size_t)(b * PROW + row)) * HD + h;
  const _Float16 hv = (_Float16)v;
  padF[o] = hv;
  padB[o] = hv;
}

// ===========================================================================
// 256x256-tile conv GEMM, 1024 threads = 16 waves (4M x 4N), wave tile 64x64.
// Single-buffered 4 regions (256x32 f16 = 16 KB each, 64 KB total); region
// liveness: A0 read P0; B0 read P0,P1; A1 read P2; B1 read P2,P3. Stage of
// next-kt region right after it goes dead:
//   P0: stage B1[kt]   P1: stage A0[kt+1]  P2: stage B0[kt+1]  P3: stage A1[kt+1]
// Counted vmcnt at P1/P3-END (before end barrier) -> next phases' reads are
// pre-barrier-safe. Phase = [ds_reads; stage; SBAR; lgkm0; MFMA; (vmcnt); SBAR].
// Tail stages read <=192B past the K extent (lands in dead regions; in-ws).
// grid 256 (1/CU), LDS 128 KiB (64 regions + full-tile epilogue).
// ===========================================================================
__global__ __launch_bounds__(1024, 4)
void conv_gemm(const _Float16* __restrict__ padFp, const _Float16* __restrict__ padBp,
               const _Float16* __restrict__ WtF, const _Float16* __restrict__ WtB,
               const float* __restrict__ biasF, const float* __restrict__ biasB,
               _Float16* __restrict__ tF, _Float16* __restrict__ tB) {
  constexpr int NT = KIN / 64;   // 40
  __shared__ alignas(16) _Float16 LDSA[65536];   // 128 KiB

  const int id  = blockIdx.x;          // 256 blocks
  const int xcd = id & 7;
  const int dir = xcd >> 2;
  const int nt  = (xcd >> 1) & 1;
  const int mt  = (xcd & 1) * 32 + (id >> 3);

  const _Float16* pad = dir ? padBp : padFp;
  const _Float16* Wt  = dir ? WtB : WtF;
  const float* bias   = dir ? biasB : biasF;
  _Float16* outT      = dir ? tB : tF;
  const int off = dir ? WID : 0;

  const int m0 = mt * 256, n0 = nt * 256;
  const int b  = m0 >> 9, t0 = m0 & (SQ - 1);
  const int arow0 = b * PROW + t0 + off;

  const int tid  = threadIdx.x;
  const int lane = tid & 63, wv = tid >> 6;     // wv 0..15
  const int wm = wv >> 2, wn = wv & 3;          // 4M x 4N waves
  const int lr = lane & 15, q = lane >> 4;

  _Float16* A0 = LDSA;
  _Float16* B0 = LDSA + 8192;
  _Float16* A1 = LDSA + 16384;
  _Float16* B1 = LDSA + 24576;

  const int r   = tid >> 2;                               // 0..255
  const int csw = ((tid & 3) ^ ((r >> 1) & 3)) << 3;      // swizzled k-chunk
  // Windowed A is a linear slab: (arow0+r+kseg)*HD + h0 == (arow0+r)*HD + kk.
  const _Float16* pA = pad + (size_t)(arow0 + r) * HD + csw;
  const _Float16* pB = Wt + (size_t)(n0 + r) * KIN + csw;
  _Float16* dA0 = A0 + tid * 8;
  _Float16* dB0 = B0 + tid * 8;
  _Float16* dA1 = A1 + tid * 8;
  _Float16* dB1 = B1 + tid * 8;

  f32x4 acc[4][4] = {};

  // Prologue: A0[0], B0[0], A1[0] (order matters for the vmcnt ledger)
  gld16(dA0, pA);
  gld16(dB0, pB);
  gld16(dA1, pA + 32);
  VMCNT(1);           // A0[0], B0[0] complete
  SBAR();

#pragma unroll 1
  for (int kt = 0; kt < NT; ++kt) {
    f16x8 aF[4], bF[2];
    // ---- P0: A0 + B0(nj 0,1)
#pragma unroll
    for (int mi = 0; mi < 4; ++mi) aF[mi] = rdfrag(A0, wm * 64 + mi * 16 + lr, q);
#pragma unroll
    for (int nj = 0; nj < 2; ++nj) bF[nj] = rdfrag(B0, wn * 64 + nj * 16 + lr, q);
    gld16(dB1, pB + 32);                 // B1[kt]
    SBAR(); LGKM0();
    __builtin_amdgcn_s_setprio(1);
#pragma unroll
    for (int mi = 0; mi < 4; ++mi)
#pragma unroll
      for (int nj = 0; nj < 2; ++nj)
        acc[mi][nj] = __builtin_amdgcn_mfma_f32_16x16x32_f16(aF[mi], bF[nj], acc[mi][nj], 0, 0, 0);
    __builtin_amdgcn_s_setprio(0);
    SBAR();
    // ---- P1: B0(nj 2,3), reuse aF
#pragma unroll
    for (int nj = 0; nj < 2; ++nj) bF[nj] = rdfrag(B0, wn * 64 + (nj + 2) * 16 + lr, q);
    gld16(dA0, pA + 64);                 // A0[kt+1]
    SBAR(); LGKM0();
    __builtin_amdgcn_s_setprio(1);
#pragma unroll
    for (int mi = 0; mi < 4; ++mi)
#pragma unroll
      for (int nj = 0; nj < 2; ++nj)
        acc[mi][nj + 2] = __builtin_amdgcn_mfma_f32_16x16x32_f16(aF[mi], bF[nj], acc[mi][nj + 2], 0, 0, 0);
    __builtin_amdgcn_s_setprio(0);
    VMCNT(1);          // A1[kt], B1[kt] complete (before barrier -> P2 reads safe)
    SBAR();
    // ---- P2: A1 + B1(nj 0,1)
#pragma unroll
    for (int mi = 0; mi < 4; ++mi) aF[mi] = rdfrag(A1, wm * 64 + mi * 16 + lr, q);
#pragma unroll
    for (int nj = 0; nj < 2; ++nj) bF[nj] = rdfrag(B1, wn * 64 + nj * 16 + lr, q);
    gld16(dB0, pB + 64);                 // B0[kt+1]
    SBAR(); LGKM0();
    __builtin_amdgcn_s_setprio(1);
#pragma unroll
    for (int mi = 0; mi < 4; ++mi)
#pragma unroll
      for (int nj = 0; nj < 2; ++nj)
        acc[mi][nj] = __builtin_amdgcn_mfma_f32_16x16x32_f16(aF[mi], bF[nj], acc[mi][nj], 0, 0, 0);
    __builtin_amdgcn_s_setprio(0);
    SBAR();
    // ---- P3: B1(nj 2,3), reuse aF
#pragma unroll
    for (int nj = 0; nj < 2; ++nj) bF[nj] = rdfrag(B1, wn * 64 + (nj + 2) * 16 + lr, q);
    gld16(dA1, pA + 96);                 // A1[kt+1]
    SBAR(); LGKM0();
    __builtin_amdgcn_s_setprio(1);
#pragma unroll
    for (int mi = 0; mi < 4; ++mi)
#pragma unroll
      for (int nj = 0; nj < 2; ++nj)
        acc[mi][nj + 2] = __builtin_amdgcn_mfma_f32_16x16x32_f16(aF[mi], bF[nj], acc[mi][nj + 2], 0, 0, 0);
    __builtin_amdgcn_s_setprio(0);
    VMCNT(1);          // A0[kt+1], B0[kt+1] complete -> next P0 reads safe
    SBAR();
    pA += 64; pB += 64;
  }

  // ---- Epilogue
  VMCNT(0);
  SBAR();
#pragma unroll
  for (int nj = 0; nj < 4; ++nj) {
    const int col = wn * 64 + nj * 16 + lr;
    const float bv = bias[n0 + col];
#pragma unroll
    for (int mi = 0; mi < 4; ++mi)
#pragma unroll
      for (int g = 0; g < 4; ++g) {
        const int row = wm * 64 + mi * 16 + q * 4 + g;
        float v = acc[mi][nj][g] + bv;
        v = v > 0.f ? v : 0.f;
        LDSA[row * 256 + (((col >> 3) ^ ((row >> 2) & 7)) << 3) + (col & 7)] = (_Float16)v;
      }
  }
  LGKM0();
  SBAR();
#pragma unroll
  for (int j = 0; j < 8; ++j) {
    const int cid = j * 1024 + tid;
    const int row = cid >> 5, c = cid & 31;
    f16x8 v8 = *(const f16x8*)&LDSA[row * 256 + ((c ^ ((row >> 2) & 7)) << 3)];
    *(f16x8*)&outT[(size_t)(m0 + row) * HD + n0 + c * 8] = v8;
  }
}

// ===========================================================================
// 256x256-tile highway GEMM, same schedule. Weights pre-interleaved (row 2j =
// nonlin col j, row 2j+1 = gate col j) -> block covers 128 output pairs.
// mode 0: fp16 oh. mode 1: fp16 into next pad interior AND fp32 out32.
// mode 2: fp32 out32 only.  grid 512.
// ===========================================================================
__global__ __launch_bounds__(1024, 4)
void hw_gemm(const _Float16* __restrict__ xF, const _Float16* __restrict__ xB,
             const _Float16* __restrict__ WtFp, const _Float16* __restrict__ WtBp,
             const float* __restrict__ bFp, const float* __restrict__ bBp,
             _Float16* __restrict__ oFp, _Float16* __restrict__ oBp,
             float* __restrict__ out32, int mode) {
  constexpr int NT = HD / 64;   // 8
  __shared__ alignas(16) _Float16 LDSA[65536];

  const int id  = blockIdx.x;          // 512 blocks
  const int xcd = id & 7;
  const int dir = xcd >> 2;
  const int nt  = xcd & 3;
  const int mt  = id >> 3;

  const _Float16* x  = dir ? xB : xF;
  const _Float16* Wt = dir ? WtBp : WtFp;
  const float* bias  = dir ? bBp : bFp;
  _Float16* oh       = dir ? oBp : oFp;

  const int m0 = mt * 256, n0 = nt * 256;

  const int tid  = threadIdx.x;
  const int lane = tid & 63, wv = tid >> 6;
  const int wm = wv >> 2, wn = wv & 3;
  const int lr = lane & 15, q = lane >> 4;

  _Float16* A0 = LDSA;
  _Float16* B0 = LDSA + 8192;
  _Float16* A1 = LDSA + 16384;
  _Float16* B1 = LDSA + 24576;

  const int r   = tid >> 2;
  const int csw = ((tid & 3) ^ ((r >> 1) & 3)) << 3;
  const _Float16* pA = x + (size_t)(m0 + r) * HD + csw;
  const _Float16* pB = Wt + (size_t)(n0 + r) * HD + csw;
  _Float16* dA0 = A0 + tid * 8;
  _Float16* dB0 = B0 + tid * 8;
  _Float16* dA1 = A1 + tid * 8;
  _Float16* dB1 = B1 + tid * 8;

  f32x4 acc[4][4] = {};

  gld16(dA0, pA);
  gld16(dB0, pB);
  gld16(dA1, pA + 32);
  VMCNT(1);
  SBAR();

#pragma unroll 1
  for (int kt = 0; kt < NT; ++kt) {
    f16x8 aF[4], bF[2];
    // P0
#pragma unroll
    for (int mi = 0; mi < 4; ++mi) aF[mi] = rdfrag(A0, wm * 64 + mi * 16 + lr, q);
#pragma unroll
    for (int nj = 0; nj < 2; ++nj) bF[nj] = rdfrag(B0, wn * 64 + nj * 16 + lr, q);
    gld16(dB1, pB + 32);
    SBAR(); LGKM0();
    __builtin_amdgcn_s_setprio(1);
#pragma unroll
    for (int mi = 0; mi < 4; ++mi)
#pragma unroll
      for (int nj = 0; nj < 2; ++nj)
        acc[mi][nj] = __builtin_amdgcn_mfma_f32_16x16x32_f16(aF[mi], bF[nj], acc[mi][nj], 0, 0, 0);
    __builtin_amdgcn_s_setprio(0);
    SBAR();
    // P1
#pragma unroll
    for (int nj = 0; nj < 2; ++nj) bF[nj] = rdfrag(B0, wn * 64 + (nj + 2) * 16 + lr, q);
    gld16(dA0, pA + 64);
    SBAR(); LGKM0();
    __builtin_amdgcn_s_setprio(1);
#pragma unroll
    for (int mi = 0; mi < 4; ++mi)
#pragma unroll
      for (int nj = 0; nj < 2; ++nj)
        acc[mi][nj + 2] = __builtin_amdgcn_mfma_f32_16x16x32_f16(aF[mi], bF[nj], acc[mi][nj + 2], 0, 0, 0);
    __builtin_amdgcn_s_setprio(0);
    VMCNT(1);
    SBAR();
    // P2
#pragma unroll
    for (int mi = 0; mi < 4; ++mi) aF[mi] = rdfrag(A1, wm * 64 + mi * 16 + lr, q);
#pragma unroll
    for (int nj = 0; nj < 2; ++nj) bF[nj] = rdfrag(B1, wn * 64 + nj * 16 + lr, q);
    gld16(dB0, pB + 64);
    SBAR(); LGKM0();
    __builtin_amdgcn_s_setprio(1);
#pragma unroll
    for (int mi = 0; mi < 4; ++mi)
#pragma unroll
      for (int nj = 0; nj < 2; ++nj)
        acc[mi][nj] = __builtin_amdgcn_mfma_f32_16x16x32_f16(aF[mi], bF[nj], acc[mi][nj], 0, 0, 0);
    __builtin_amdgcn_s_setprio(0);
    SBAR();
    // P3
#pragma unroll
    for (int nj = 0; nj < 2; ++nj) bF[nj] = rdfrag(B1, wn * 64 + (nj + 2) * 16 + lr, q);
    gld16(dA1, pA + 96);
    SBAR(); LGKM0();
    __builtin_amdgcn_s_setprio(1);
#pragma unroll
    for (int mi = 0; mi < 4; ++mi)
#pragma unroll
      for (int nj = 0; nj < 2; ++nj)
        acc[mi][nj + 2] = __builtin_amdgcn_mfma_f32_16x16x32_f16(aF[mi], bF[nj], acc[mi][nj + 2], 0, 0, 0);
    __builtin_amdgcn_s_setprio(0);
    VMCNT(1);
    SBAR();
    pA += 64; pB += 64;
  }

  // Epilogue: proj (+bias) -> swizzled LDS; paired gate combine on readback.
  VMCNT(0);
  SBAR();
#pragma unroll
  for (int nj = 0; nj < 4; ++nj) {
    const int col = wn * 64 + nj * 16 + lr;
    const int gcol = n0 + col;
    const float bv = bias[((gcol & 1) << 9) + (gcol >> 1)];
#pragma unroll
    for (int mi = 0; mi < 4; ++mi)
#pragma unroll
      for (int g = 0; g < 4; ++g) {
        const int row = wm * 64 + mi * 16 + q * 4 + g;
        LDSA[row * 256 + (((col >> 3) ^ ((row >> 2) & 7)) << 3) + (col & 7)] =
            (_Float16)(acc[mi][nj][g] + bv);
      }
  }
  LGKM0();
  SBAR();
#pragma unroll
  for (int j = 0; j < 4; ++j) {
    const int cid = j * 1024 + tid;
    const int row = cid >> 4, pc = cid & 15;
    const int s = (row >> 2) & 7;
    f16x8 u = *(const f16x8*)&LDSA[row * 256 + (((pc * 2) ^ s) << 3)];
    f16x8 v = *(const f16x8*)&LDSA[row * 256 + (((pc * 2 + 1) ^ s) << 3)];
    const int xrow = m0 + row;
    const int oc0 = (n0 >> 1) + pc * 8;
    f16x8 xv8 = *(const f16x8*)&x[(size_t)xrow * HD + oc0];
    f16x8 o8;
    float of[8];
#pragma unroll
    for (int e = 0; e < 8; ++e) {
      float nl = (e < 4) ? (float)u[2 * e]     : (float)v[2 * e - 8];
      float gz = (e < 4) ? (float)u[2 * e + 1] : (float)v[2 * e - 7];
      nl = nl > 0.f ? nl : 0.f;
      const float gt = 1.f / (1.f + __expf(-gz));
      const float o = gt * (float)xv8[e] + (1.f - gt) * nl;
      of[e] = o;
      o8[e] = (_Float16)o;
    }
    if (mode == 0) {
      *(f16x8*)&oh[(size_t)xrow * HD + oc0] = o8;
    } else {
      if (mode == 1) {
        const int bb = xrow >> 9, tt = xrow & (SQ - 1);
        *(f16x8*)&oh[((size_t)(bb * PROW + WID + tt)) * HD + oc0] = o8;
      }
      float* op = out32 + (size_t)xrow * (2 * HD) + dir * HD + oc0;
      *(float4*)op = make_float4(of[0], of[1], of[2], of[3]);
      *(float4*)(op + 4) = make_float4(of[4], of[5], of[6], of[7]);
    }
  }
}

// ---------------------------------------------------------------------------
extern "C" void kernel_launch(void* const* d_in, const int* in_sizes, int n_in,
                              void* d_out, int out_size, void* d_ws, size_t ws_size,
                              hipStream_t stream) {
  const float* inputs   = (const float*)d_in[0];
  const float* fwd_pads = (const float*)d_in[2];   // [3][4][512]
  const float* bwd_pads = (const float*)d_in[3];
  const float* fwd_W    = (const float*)d_in[4];   // [3][2560][512]
  const float* fwd_b    = (const float*)d_in[5];   // [3][512]
  const float* bwd_W    = (const float*)d_in[6];
  const float* bwd_b    = (const float*)d_in[7];
  const float* fwd_hw_W = (const float*)d_in[8];   // [3][2][512][1024]
  const float* fwd_hw_b = (const float*)d_in[9];   // [3][2][1024]
  const float* bwd_hw_W = (const float*)d_in[10];
  const float* bwd_hw_b = (const float*)d_in[11];
  float* out = (float*)d_out;

  char* p = (char*)d_ws;
  auto take = [&](size_t n) { char* r = p; p += (n + 255) & ~(size_t)255; return r; };

  _Float16* padF = (_Float16*)take((size_t)LAY * PSTR * 2);
  _Float16* padB = (_Float16*)take((size_t)LAY * PSTR * 2);
  _Float16* tF   = (_Float16*)take((size_t)MR * HD * 2);
  _Float16* tB   = (_Float16*)take((size_t)MR * HD * 2);
  _Float16* uF   = (_Float16*)take((size_t)MR * HD * 2);
  _Float16* uB   = (_Float16*)take((size_t)MR * HD * 2);
  _Float16* WtcF = (_Float16*)take((size_t)LAY * HD * KIN * 2);
  _Float16* WtcB = (_Float16*)take((size_t)LAY * HD * KIN * 2);
  _Float16* WthF = (_Float16*)take((size_t)LAY * 2 * (2 * HD) * HD * 2);
  _Float16* WthB = (_Float16*)take((size_t)LAY * 2 * (2 * HD) * HD * 2);

  transpose_w2<<<dim3(HD / 32, KIN / 32, 2 * LAY), dim3(32, 8), 0, stream>>>(
      fwd_W, bwd_W, WtcF, WtcB, KIN, HD, LAY, 0);
  transpose_w2<<<dim3((2 * HD) / 32, HD / 32, 2 * LAY * 2), dim3(32, 8), 0, stream>>>(
      fwd_hw_W, bwd_hw_W, WthF, WthB, HD, 2 * HD, LAY * 2, 1);

  init_interior<<<(NB * SQ * HD / 4) / 256, 256, 0, stream>>>((const float4*)inputs, padF, padB);
  fill_all_pads<<<(LAY * 2 * NB * WID * HD) / 256, 256, 0, stream>>>(fwd_pads, bwd_pads, padF, padB);

  for (int i = 0; i < LAY; ++i) {
    _Float16* pF = padF + (size_t)i * PSTR;
    _Float16* pB = padB + (size_t)i * PSTR;
    const int nx = (i + 1 < LAY) ? (i + 1) : 0;
    _Float16* nF = padF + (size_t)nx * PSTR;
    _Float16* nB = padB + (size_t)nx * PSTR;

    conv_gemm<<<dim3(256), dim3(1024), 0, stream>>>(
        pF, pB,
        WtcF + (size_t)i * HD * KIN, WtcB + (size_t)i * HD * KIN,
        fwd_b + (size_t)i * HD, bwd_b + (size_t)i * HD, tF, tB);
    hw_gemm<<<dim3(512), dim3(1024), 0, stream>>>(
        tF, tB,
        WthF + (size_t)(i * 2 + 0) * (2 * HD) * HD, WthB + (size_t)(i * 2 + 0) * (2 * HD) * HD,
        fwd_hw_b + (size_t)(i * 2 + 0) * (2 * HD), bwd_hw_b + (size_t)(i * 2 + 0) * (2 * HD),
        uF, uB, nullptr, 0);
    hw_gemm<<<dim3(512), dim3(1024), 0, stream>>>(
        uF, uB,
        WthF + (size_t)(i * 2 + 1) * (2 * HD) * HD, WthB + (size_t)(i * 2 + 1) * (2 * HD) * HD,
        fwd_hw_b + (size_t)(i * 2 + 1) * (2 * HD), bwd_hw_b + (size_t)(i * 2 + 1) * (2 * HD),
        nF, nB, out + (size_t)i * MR * (2 * HD), (i + 1 < LAY) ? 1 : 2);
  }
}